// Round 3
// baseline (1201.713 us; speedup 1.0000x reference)
//
#include <hip/hip_runtime.h>

// IF-neuron, exact fp64 strategy (round 2 passed, absmax 0.0 -> np ref is fp64).
// This round: f64 MFMA GEMM fused with the scan. The D-fragment layout of
// v_mfma_f64_16x16x4f64 is discovered AT RUNTIME with two probe MFMAs
// (round 0's failure signature = row-permuted outputs = wrong D-row mapping).
// A/B layouts assumed standard (lane l: A[l&15][l>>4], B[l>>4][l&15]); a
// validity check on the probe results falls back to scalar-f64 dots if wrong.

#define T_STEPS 32
#define B_DIM   128
#define K_DIM   2048
#define O_DIM   2048

typedef double d4 __attribute__((ext_vector_type(4)));

// ---- prepass: W[o][k] -> wf[ot][k][i] = W[ot*16+i][k] ----
__global__ __launch_bounds__(256) void prep_w(const float* __restrict__ Wm,
                                              float* __restrict__ wf) {
    __shared__ float lds[16][65];
    const int kc = blockIdx.x, ot = blockIdx.y;
    const int k0 = kc * 64, o0 = ot * 16;
    const int c = threadIdx.x & 63;
    const int r4 = threadIdx.x >> 6;
#pragma unroll
    for (int rr = 0; rr < 4; ++rr) {
        int r = r4 * 4 + rr;
        lds[r][c] = Wm[(size_t)(o0 + r) * K_DIM + k0 + c];
    }
    __syncthreads();
    float* dst = wf + (size_t)ot * (K_DIM * 16) + (size_t)k0 * 16;
#pragma unroll
    for (int q = 0; q < 4; ++q) {
        int f = q * 256 + threadIdx.x;
        dst[f] = lds[f & 15][f >> 4];
    }
}

// ---- prepass: inp[t][b][k] -> af[t][bt][k][i] = inp[t][bt*16+i][k] ----
__global__ __launch_bounds__(256) void prep_a(const float* __restrict__ inp,
                                              float* __restrict__ af) {
    __shared__ float lds[16][65];
    const int kc = blockIdx.x, bt = blockIdx.y, t = blockIdx.z;
    const int k0 = kc * 64;
    const float* src = inp + (size_t)t * (B_DIM * K_DIM) + (size_t)(bt * 16) * K_DIM + k0;
    const int c = threadIdx.x & 63;
    const int r4 = threadIdx.x >> 6;
#pragma unroll
    for (int rr = 0; rr < 4; ++rr) {
        int r = r4 * 4 + rr;
        lds[r][c] = src[(size_t)r * K_DIM + c];
    }
    __syncthreads();
    float* dst = af + (size_t)t * (B_DIM * K_DIM) + (size_t)bt * (K_DIM * 16) + (size_t)k0 * 16;
#pragma unroll
    for (int q = 0; q < 4; ++q) {
        int f = q * 256 + threadIdx.x;
        dst[f] = lds[f & 15][f >> 4];
    }
}

// ---- fused f64-MFMA GEMM + IF scan ----
// grid (32, 8), 256 threads = 4 waves; wave w owns 16x16 tile (b0, o0 + w*16).
template <bool PRE>
__global__ __launch_bounds__(256) void if_main(
    const float* __restrict__ af, const float* __restrict__ wf,
    const float* __restrict__ inp, const float* __restrict__ Wm,
    const float* __restrict__ bias, const float* __restrict__ mem0,
    float* __restrict__ outp)
{
    const int tid = threadIdx.x;
    const int l   = tid & 63;
    const int wv  = tid >> 6;
    const int o0  = blockIdx.x * 64 + wv * 16;
    const int b0  = blockIdx.y * 16;
    const int col = l & 15;
    const int g   = l >> 4;

    // ---- runtime D-layout probe (2 MFMAs) ----
    // A[m][k] = (k==0)? m : 0  -> lane value (g==0)? col : 0
    // B[k][n] = (k==0)? 1 : 0  -> lane value (g==0)? 1   : 0
    const double p_val = (g == 0) ? (double)col : 0.0;
    const double p_one = (g == 0) ? 1.0 : 0.0;
    d4 z = {0.0, 0.0, 0.0, 0.0};
    d4 dr = __builtin_amdgcn_mfma_f64_16x16x4f64(p_val, p_one, z, 0, 0, 0); // D=row idx
    d4 dc = __builtin_amdgcn_mfma_f64_16x16x4f64(p_one, p_val, z, 0, 0, 0); // D=col idx

    int rix[4], cix[4];
    bool okl = true;
#pragma unroll
    for (int j = 0; j < 4; ++j) {
        double r = dr[j], c = dc[j];
        bool rin = (r >= 0.0) && (r < 16.0);
        bool cin = (c >= 0.0) && (c < 16.0);
        int ri = rin ? (int)r : 0;
        int ci = cin ? (int)c : 0;
        okl = okl && rin && cin && ((double)ri == r) && ((double)ci == c);
        rix[j] = ri; cix[j] = ci;
    }
#pragma unroll
    for (int a = 0; a < 4; ++a)
#pragma unroll
        for (int b2 = a + 1; b2 < 4; ++b2)
            okl = okl && !(rix[a] == rix[b2] && cix[a] == cix[b2]);
    const bool ok = (__all(okl ? 1 : 0) != 0);
    if (!ok) {
        // fallback owns its own mapping (no MFMA involved)
#pragma unroll
        for (int j = 0; j < 4; ++j) { rix[j] = g * 4 + j; cix[j] = col; }
    }

    double mem[4], biasd[4];
    int cnt[4]; bool sp[4];
#pragma unroll
    for (int j = 0; j < 4; ++j) {
        const int o = o0 + cix[j];
        biasd[j] = (double)bias[o];
        mem[j]   = (double)mem0[(size_t)(b0 + rix[j]) * O_DIM + o];
        sp[j] = false; cnt[j] = 0;
    }

    const float* pa = nullptr;
    const float* pw = nullptr;
    if (PRE) {
        pa = af + (size_t)blockIdx.y * (K_DIM * 16) + l;
        pw = wf + (size_t)(blockIdx.x * 4 + wv) * (K_DIM * 16) + l;
    }

    for (int t = 0; t < T_STEPS; ++t) {
        d4 xs;
        if (ok) {
            d4 acc0 = {0.0, 0.0, 0.0, 0.0};
            d4 acc1 = {0.0, 0.0, 0.0, 0.0};
            const float* pat = PRE ? (pa + (size_t)t * (B_DIM * K_DIM)) : nullptr;
            const float* pit = PRE ? nullptr : (inp + (size_t)t * (B_DIM * K_DIM));
#pragma unroll 4
            for (int k0 = 0; k0 < K_DIM; k0 += 8) {
                double a0, w0, a1, w1;
                if (PRE) {
                    a0 = (double)pat[k0 * 16];
                    w0 = (double)pw[k0 * 16];
                    a1 = (double)pat[k0 * 16 + 64];
                    w1 = (double)pw[k0 * 16 + 64];
                } else {
                    a0 = (double)pit[(size_t)(b0 + col) * K_DIM + k0 + g];
                    w0 = (double)Wm[(size_t)(o0 + col) * K_DIM + k0 + g];
                    a1 = (double)pit[(size_t)(b0 + col) * K_DIM + k0 + 4 + g];
                    w1 = (double)Wm[(size_t)(o0 + col) * K_DIM + k0 + 4 + g];
                }
                acc0 = __builtin_amdgcn_mfma_f64_16x16x4f64(a0, w0, acc0, 0, 0, 0);
                acc1 = __builtin_amdgcn_mfma_f64_16x16x4f64(a1, w1, acc1, 0, 0, 0);
            }
#pragma unroll
            for (int j = 0; j < 4; ++j) xs[j] = acc0[j] + acc1[j];
        } else {
            // scalar-f64 safety net (correct for any HW layout surprise)
#pragma unroll
            for (int j = 0; j < 4; ++j) {
                const float* ar = inp + ((size_t)t * B_DIM + b0 + rix[j]) * K_DIM;
                const float* wr = Wm + (size_t)(o0 + cix[j]) * K_DIM;
                double s0 = 0.0, s1 = 0.0;
                for (int k = 0; k < K_DIM; k += 2) {
                    s0 = fma((double)ar[k],     (double)wr[k],     s0);
                    s1 = fma((double)ar[k + 1], (double)wr[k + 1], s1);
                }
                xs[j] = s0 + s1;
            }
        }
#pragma unroll
        for (int j = 0; j < 4; ++j) {
            double m_ = (sp[j] ? 0.0 : mem[j]) + (xs[j] + biasd[j]);
            sp[j]  = (m_ > 1.0);
            mem[j] = m_;
            cnt[j] += sp[j] ? 1 : 0;
        }
    }

#pragma unroll
    for (int j = 0; j < 4; ++j)
        outp[(size_t)(b0 + rix[j]) * O_DIM + o0 + cix[j]] = (float)cnt[j] * 0.03125f;
}

extern "C" void kernel_launch(void* const* d_in, const int* in_sizes, int n_in,
                              void* d_out, int out_size, void* d_ws, size_t ws_size,
                              hipStream_t stream) {
    const float* inp  = (const float*)d_in[0];   // [32,128,2048]
    const float* Wm   = (const float*)d_in[1];   // [2048,2048]
    const float* bias = (const float*)d_in[2];   // [2048]
    const float* mem0 = (const float*)d_in[3];   // [128,2048]
    float* outp = (float*)d_out;                 // [128,2048]

    const size_t wf_elems = (size_t)O_DIM * K_DIM;           // 16 MB
    const size_t af_elems = (size_t)T_STEPS * B_DIM * K_DIM; // 32 MB
    const size_t need = (wf_elems + af_elems) * sizeof(float);

    if (ws_size >= need) {
        float* wf = (float*)d_ws;
        float* af = wf + wf_elems;
        prep_w<<<dim3(32, 128), 256, 0, stream>>>(Wm, wf);
        prep_a<<<dim3(32, 8, 32), 256, 0, stream>>>(inp, af);
        if_main<true><<<dim3(32, 8), 256, 0, stream>>>(af, wf, inp, Wm, bias, mem0, outp);
    } else {
        if_main<false><<<dim3(32, 8), 256, 0, stream>>>(nullptr, nullptr, inp, Wm, bias, mem0, outp);
    }
}